// Round 7
// baseline (277.381 us; speedup 1.0000x reference)
//
#include <hip/hip_runtime.h>
#include <math.h>

// GCN 2-layer, pull-based (CSR by dst via counting sort), no float atomics.
// Algebra: segsum commutes with right-matmul -> both matmuls hoisted:
//   fW1 = feat@W1 (one pass over N rows)
//   h   = relu(segsum(fW1[src]) + b1)
//   p   = h@W2 (compact per-node) ; out = softmax(segsum(p[src]) + b2)
// R6: hist atomics were line-contention bound (1.6M atomics over 6400 lines,
//     ~250 hits/line -> prep 115us at 0.9TB/s effective). Shard counters x8
//     (node-major [n][s] layout keeps node segments contiguous), int4 edge
//     loads (4 edges/thread), deeper layer1 unroll (16 edges in flight).

#define SCAN_B 1024
#define FW1B   1024   // blocks of the fused grid doing fw1

// ---------------- fused prep: blocks [0,FW1B) do fW1=feat@W1, rest hist ----------------
// hist blocks: 4 edges/thread via int4; shard s = (e>>10)&(S-1) (constant per
// 1024-edge block, recomputable in fill). rank = atomicAdd return value.
__global__ __launch_bounds__(256) void prep_kernel(
    const float* __restrict__ feat, const float* __restrict__ W1,
    float* __restrict__ fW1, const int* __restrict__ dst,
    int* __restrict__ counts, int* __restrict__ rank, int n_nodes, int E, int S)
{
    if ((int)blockIdx.x >= FW1B) {
        int hb = (int)blockIdx.x - FW1B;
        int e0 = hb * 1024 + (int)threadIdx.x * 4;
        if (e0 >= E) return;
        int s = (e0 >> 10) & (S - 1);
        if (e0 + 3 < E) {
            int4 d = ((const int4*)dst)[e0 >> 2];
            int r0 = atomicAdd(&counts[(size_t)d.x * S + s], 1);
            int r1 = atomicAdd(&counts[(size_t)d.y * S + s], 1);
            int r2 = atomicAdd(&counts[(size_t)d.z * S + s], 1);
            int r3 = atomicAdd(&counts[(size_t)d.w * S + s], 1);
            ((int4*)rank)[e0 >> 2] = make_int4(r0, r1, r2, r3);
        } else {
            for (int e = e0; e < E; ++e)
                rank[e] = atomicAdd(&counts[(size_t)dst[e] * S + s], 1);
        }
        return;
    }
    // ---- fW1 part: W1 staged in LDS once per block, wave per node ----
    __shared__ float w1s[4096];
    for (int i = threadIdx.x; i < 4096; i += 256) w1s[i] = W1[i];
    __syncthreads();
    int lane = threadIdx.x & 63, w = threadIdx.x >> 6;
    for (int node = (int)blockIdx.x * 4 + w; node < n_nodes; node += FW1B * 4) {
        float r = feat[(size_t)node * 64 + lane];
        float a0 = 0.f, a1 = 0.f;
#pragma unroll
        for (int k = 0; k < 64; k += 2) {
            a0 = fmaf(__shfl(r, k, 64),     w1s[k * 64 + lane],       a0);
            a1 = fmaf(__shfl(r, k + 1, 64), w1s[(k + 1) * 64 + lane], a1);
        }
        fW1[(size_t)node * 64 + lane] = a0 + a1;
    }
}

// ---------------- scan (over n = N*S counters) ----------------
__global__ void scan_phaseA(const int* __restrict__ counts, int* __restrict__ excl,
                            int* __restrict__ blocksums, int n) {
    __shared__ int lds[SCAN_B];
    int tid = threadIdx.x;
    int i = blockIdx.x * SCAN_B + tid;
    int v = (i < n) ? counts[i] : 0;
    lds[tid] = v;
    __syncthreads();
    for (int off = 1; off < SCAN_B; off <<= 1) {
        int t = (tid >= off) ? lds[tid - off] : 0;
        __syncthreads();
        lds[tid] += t;
        __syncthreads();
    }
    if (i < n) excl[i] = lds[tid] - v;
    if (tid == SCAN_B - 1) blocksums[blockIdx.x] = lds[SCAN_B - 1];
}

__global__ void scan_phaseB(int* blocksums, int nb) {
    __shared__ int lds[SCAN_B];
    int tid = threadIdx.x;
    int v = (tid < nb) ? blocksums[tid] : 0;
    lds[tid] = v;
    __syncthreads();
    for (int off = 1; off < SCAN_B; off <<= 1) {
        int t = (tid >= off) ? lds[tid - off] : 0;
        __syncthreads();
        lds[tid] += t;
        __syncthreads();
    }
    if (tid < nb) blocksums[tid] = lds[tid] - v;
}

__global__ void scan_phaseC(int* __restrict__ offs, const int* __restrict__ blocksums,
                            int* __restrict__ cursor, int n, int E) {
    int i = blockIdx.x * blockDim.x + threadIdx.x;
    if (i < n) {
        int o = offs[i] + blocksums[i / SCAN_B];
        offs[i] = o;
        if (cursor) cursor[i] = o;
    } else if (i == n) {
        offs[n] = E;
    }
}

// ---------------- fill: atomic-free via (shard, rank) ----------------
__global__ void fill_rank_kernel(const int* __restrict__ src, const int* __restrict__ dst,
                                 const int* __restrict__ rank, const int* __restrict__ offs,
                                 int* __restrict__ ssort, int E, int S) {
    int e0 = ((int)blockIdx.x * 256 + (int)threadIdx.x) * 4;
    if (e0 >= E) return;
    int s = (e0 >> 10) & (S - 1);
    if (e0 + 3 < E) {
        int4 d = ((const int4*)dst)[e0 >> 2];
        int4 sr = ((const int4*)src)[e0 >> 2];
        int4 r = ((const int4*)rank)[e0 >> 2];
        ssort[offs[(size_t)d.x * S + s] + r.x] = sr.x;
        ssort[offs[(size_t)d.y * S + s] + r.y] = sr.y;
        ssort[offs[(size_t)d.z * S + s] + r.z] = sr.z;
        ssort[offs[(size_t)d.w * S + s] + r.w] = sr.w;
    } else {
        for (int e = e0; e < E; ++e)
            ssort[offs[(size_t)dst[e] * S + s] + rank[e]] = src[e];
    }
}

// fallback when rank[] doesn't fit: sharded cursor atomics
__global__ void fill_cursor_kernel(const int* __restrict__ src, const int* __restrict__ dst,
                                   int* __restrict__ cursor, int* __restrict__ ssort,
                                   int E, int S) {
    int e0 = ((int)blockIdx.x * 256 + (int)threadIdx.x) * 4;
    if (e0 >= E) return;
    int s = (e0 >> 10) & (S - 1);
    for (int e = e0; e < e0 + 4 && e < E; ++e) {
        int pos = atomicAdd(&cursor[(size_t)dst[e] * S + s], 1);
        ssort[pos] = src[e];
    }
}

// ------- layer1 tail: b1 + relu + compact dense2 (h@W2 -> p) -------
__device__ __forceinline__ void layer1_tail(float acc, int lane, int node,
                                            const float* __restrict__ b1,
                                            const float* __restrict__ W2,
                                            float* __restrict__ p)
{
    float h = fmaxf(acc + b1[lane], 0.f);
    int j = lane & 15, ks = lane >> 4;
    float pp = 0.f;
#pragma unroll
    for (int i = 0; i < 16; ++i) {
        int kk = ks * 16 + i;
        float hk = __shfl(h, kk, 64);          // broadcast h[kk] from lane kk
        pp = fmaf(hk, W2[kk * 16 + j], pp);
    }
    pp += __shfl_xor(pp, 16, 64);
    pp += __shfl_xor(pp, 32, 64);
    if (ks == 0) p[(size_t)node * 16 + j] = pp;
}

// ---------- layer1: gather fW1 rows, float2/lane, up to 16 edges in flight ----------
__global__ __launch_bounds__(256) void layer1_f32_kernel(
    const float2* __restrict__ fW1_2, const int* __restrict__ offs,
    const int* __restrict__ ssort, const float* __restrict__ b1,
    const float* __restrict__ W2, float* __restrict__ p, int n_nodes, int S)
{
    int lane = threadIdx.x & 63;
    int w = threadIdx.x >> 6;
    int node = blockIdx.x * 4 + w;
    if (node >= n_nodes) return;            // no barriers below
    int beg = offs[(size_t)node * S], end = offs[(size_t)node * S + S];
    int half = lane >> 5;                   // which edge of the pair
    int sl = lane & 31;                     // col pair -> cols 2sl, 2sl+1
    float ax = 0.f, ay = 0.f;
    int k = beg + half;
    for (; k + 14 < end; k += 16) {         // 16 edges in flight per wave
        int s0 = ssort[k],      s1 = ssort[k + 2],  s2 = ssort[k + 4],  s3 = ssort[k + 6];
        int s4 = ssort[k + 8],  s5 = ssort[k + 10], s6 = ssort[k + 12], s7 = ssort[k + 14];
        float2 v0 = fW1_2[(size_t)s0 * 32 + sl];
        float2 v1 = fW1_2[(size_t)s1 * 32 + sl];
        float2 v2 = fW1_2[(size_t)s2 * 32 + sl];
        float2 v3 = fW1_2[(size_t)s3 * 32 + sl];
        float2 v4 = fW1_2[(size_t)s4 * 32 + sl];
        float2 v5 = fW1_2[(size_t)s5 * 32 + sl];
        float2 v6 = fW1_2[(size_t)s6 * 32 + sl];
        float2 v7 = fW1_2[(size_t)s7 * 32 + sl];
        ax += ((v0.x + v1.x) + (v2.x + v3.x)) + ((v4.x + v5.x) + (v6.x + v7.x));
        ay += ((v0.y + v1.y) + (v2.y + v3.y)) + ((v4.y + v5.y) + (v6.y + v7.y));
    }
    for (; k + 6 < end; k += 8) {
        int s0 = ssort[k], s1 = ssort[k + 2], s2 = ssort[k + 4], s3 = ssort[k + 6];
        float2 v0 = fW1_2[(size_t)s0 * 32 + sl];
        float2 v1 = fW1_2[(size_t)s1 * 32 + sl];
        float2 v2 = fW1_2[(size_t)s2 * 32 + sl];
        float2 v3 = fW1_2[(size_t)s3 * 32 + sl];
        ax += (v0.x + v1.x) + (v2.x + v3.x);
        ay += (v0.y + v1.y) + (v2.y + v3.y);
    }
    for (; k < end; k += 2) {
        float2 v = fW1_2[(size_t)ssort[k] * 32 + sl];
        ax += v.x;
        ay += v.y;
    }
    ax += __shfl_xor(ax, 32, 64);
    ay += __shfl_xor(ay, 32, 64);
    // redistribute (col-pair layout on 32 lanes) -> one col per lane
    float am = __shfl(ax, lane >> 1, 64);
    float bm = __shfl(ay, lane >> 1, 64);
    float acc = (lane & 1) ? bm : am;
    layer1_tail(acc, lane, node, b1, W2, p);
}

// ---------- layer2: wave/node, float2 per lane, 16 edges in flight ----------
__global__ __launch_bounds__(256) void layer2_kernel(
    const float2* __restrict__ p2, const int* __restrict__ offs,
    const int* __restrict__ ssort, const float* __restrict__ b2,
    float* __restrict__ out, int n_nodes, int S)
{
    int lane = threadIdx.x & 63;
    int w = threadIdx.x >> 6;
    int node = blockIdx.x * 4 + w;
    if (node >= n_nodes) return;
    int slot = lane >> 3;   // edge slot 0..7
    int cp = lane & 7;      // column pair -> cols 2cp, 2cp+1
    int beg = offs[(size_t)node * S], end = offs[(size_t)node * S + S];
    float ax = 0.f, ay = 0.f;
    int k = beg + slot;
    for (; k + 8 < end; k += 16) {      // 16 edges in flight
        int s0 = ssort[k], s1 = ssort[k + 8];
        float2 v0 = p2[(size_t)s0 * 8 + cp];
        float2 v1 = p2[(size_t)s1 * 8 + cp];
        ax += v0.x + v1.x;
        ay += v0.y + v1.y;
    }
    for (; k < end; k += 8) {
        float2 v = p2[(size_t)ssort[k] * 8 + cp];
        ax += v.x;
        ay += v.y;
    }
    ax += __shfl_xor(ax, 8, 64);  ay += __shfl_xor(ay, 8, 64);
    ax += __shfl_xor(ax, 16, 64); ay += __shfl_xor(ay, 16, 64);
    ax += __shfl_xor(ax, 32, 64); ay += __shfl_xor(ay, 32, 64);
    float2 bb = ((const float2*)b2)[cp];
    float vx = ax + bb.x, vy = ay + bb.y;
    float m = fmaxf(vx, vy);
    m = fmaxf(m, __shfl_xor(m, 1, 64));
    m = fmaxf(m, __shfl_xor(m, 2, 64));
    m = fmaxf(m, __shfl_xor(m, 4, 64));
    float ex = __expf(vx - m), ey = __expf(vy - m);
    float s = ex + ey;
    s += __shfl_xor(s, 1, 64);
    s += __shfl_xor(s, 2, 64);
    s += __shfl_xor(s, 4, 64);
    if (slot == 0) {
        float inv = 1.f / s;
        float2 o; o.x = ex * inv; o.y = ey * inv;
        ((float2*)out)[(size_t)node * 8 + cp] = o;
    }
}

extern "C" void kernel_launch(void* const* d_in, const int* in_sizes, int n_in,
                              void* d_out, int out_size, void* d_ws, size_t ws_size,
                              hipStream_t stream) {
    const float* feat = (const float*)d_in[0];
    const float* W1   = (const float*)d_in[1];
    const float* b1   = (const float*)d_in[2];
    const float* W2   = (const float*)d_in[3];
    const float* b2   = (const float*)d_in[4];
    const int*   src  = (const int*)d_in[5];
    const int*   dst  = (const int*)d_in[6];

    int N = in_sizes[0] / 64;
    int E = in_sizes[5];

    // choose shard count + rank availability by ws budget
    // layout: p[16N] | fW1[64N] | counts[N*S] | offs[N*S+1] | cursor[N*S] | bsums | ssort[E] | rank[E]
    auto need = [&](int S, bool rnk) -> size_t {
        size_t ints = (size_t)N * S * 3 + 1 + SCAN_B + (size_t)E + (rnk ? (size_t)E : 0);
        return ((size_t)N * 80) * 4 + ints * 4;
    };
    int S; bool use_rank;
    if (ws_size >= need(8, true))      { S = 8; use_rank = true; }
    else if (ws_size >= need(1, true)) { S = 1; use_rank = true; }
    else                               { S = 1; use_rank = false; }

    float* p      = (float*)d_ws;
    float* fW1    = p + (size_t)N * 16;
    int*   counts = (int*)(fW1 + (size_t)N * 64);
    int*   offs   = counts + (size_t)N * S;
    int*   cursor = offs + (size_t)N * S + 1;
    int*   bsums  = cursor + (size_t)N * S;
    int*   ssort  = bsums + SCAN_B;
    int*   rank   = ssort + E;
    float* out    = (float*)d_out;

    int nS = N * S;
    int nb = (nS + SCAN_B - 1) / SCAN_B;
    int histBlocks = (E + 1023) / 1024;

    hipMemsetAsync(counts, 0, (size_t)nS * sizeof(int), stream);

    prep_kernel<<<FW1B + histBlocks, 256, 0, stream>>>(
        feat, W1, fW1, dst, counts, use_rank ? rank : cursor /*dummy, overwritten*/, N, E, S);

    scan_phaseA<<<nb, SCAN_B, 0, stream>>>(counts, offs, bsums, nS);
    scan_phaseB<<<1, SCAN_B, 0, stream>>>(bsums, nb);
    scan_phaseC<<<(nS + 1 + 255) / 256, 256, 0, stream>>>(
        offs, bsums, use_rank ? nullptr : cursor, nS, E);

    if (use_rank) {
        fill_rank_kernel<<<(E + 1023) / 1024, 256, 0, stream>>>(src, dst, rank, offs, ssort, E, S);
    } else {
        fill_cursor_kernel<<<(E + 1023) / 1024, 256, 0, stream>>>(src, dst, cursor, ssort, E, S);
    }

    layer1_f32_kernel<<<(N + 3) / 4, 256, 0, stream>>>((const float2*)fW1, offs, ssort, b1, W2, p, N, S);
    layer2_kernel<<<(N + 3) / 4, 256, 0, stream>>>((const float2*)p, offs, ssort, b2, out, N, S);
}

// Round 8
// 264.191 us; speedup vs baseline: 1.0499x; 1.0499x over previous
//
#include <hip/hip_runtime.h>
#include <math.h>

// GCN 2-layer, pull-based (CSR by dst via counting sort), no float atomics.
// Algebra: segsum commutes with right-matmul -> both matmuls hoisted:
//   fW1 = feat@W1 (one pass over N rows)
//   h   = relu(segsum(fW1[src]) + b1)
//   p   = h@W2 (compact per-node) ; out = softmax(segsum(p[src]) + b2)
// R7: R6's [node][shard] sharding was a no-op (all shards in one 64B line;
//     WRITE_SIZE unchanged 81MB) and int4 hist cut atomic parallelism 4x.
//     Fix: plane-major [shard][node] counters (lines truly split x8; scan
//     reads through the transpose so offs stays node-major), hist back to
//     1 edge/thread.

#define SCAN_B 1024
#define FW1B   1024   // blocks of the fused grid doing fw1

// ---------------- fused prep: blocks [0,FW1B) do fW1=feat@W1, rest hist ----------------
// hist: 1 edge/thread; shard s=(e>>10)&(S-1) (recomputable in fill);
// counts plane-major [s][node]; rank = atomicAdd return value.
__global__ __launch_bounds__(256) void prep_kernel(
    const float* __restrict__ feat, const float* __restrict__ W1,
    float* __restrict__ fW1, const int* __restrict__ dst,
    int* __restrict__ counts, int* __restrict__ rank, int n_nodes, int E, int S)
{
    if ((int)blockIdx.x >= FW1B) {
        int e = ((int)blockIdx.x - FW1B) * 256 + threadIdx.x;
        if (e < E) {
            int s = (e >> 10) & (S - 1);
            rank[e] = atomicAdd(&counts[(size_t)s * n_nodes + dst[e]], 1);
        }
        return;
    }
    // ---- fW1 part: W1 staged in LDS once per block, wave per node ----
    __shared__ float w1s[4096];
    for (int i = threadIdx.x; i < 4096; i += 256) w1s[i] = W1[i];
    __syncthreads();
    int lane = threadIdx.x & 63, w = threadIdx.x >> 6;
    for (int node = (int)blockIdx.x * 4 + w; node < n_nodes; node += FW1B * 4) {
        float r = feat[(size_t)node * 64 + lane];
        float a0 = 0.f, a1 = 0.f;
#pragma unroll
        for (int k = 0; k < 64; k += 2) {
            a0 = fmaf(__shfl(r, k, 64),     w1s[k * 64 + lane],       a0);
            a1 = fmaf(__shfl(r, k + 1, 64), w1s[(k + 1) * 64 + lane], a1);
        }
        fW1[(size_t)node * 64 + lane] = a0 + a1;
    }
}

// ---------------- scan over n = N*S counters, scan order i=(node,S)+s ----------------
// counts is plane-major [s][node]; excl/offs are node-major [node][s].
__global__ void scan_phaseA(const int* __restrict__ counts, int* __restrict__ excl,
                            int* __restrict__ blocksums, int n, int N, int log2S) {
    __shared__ int lds[SCAN_B];
    int tid = threadIdx.x;
    int i = blockIdx.x * SCAN_B + tid;
    int Sm1 = (1 << log2S) - 1;
    int v = 0;
    if (i < n) {
        int s = i & Sm1, node = i >> log2S;
        v = counts[(size_t)s * N + node];
    }
    lds[tid] = v;
    __syncthreads();
    for (int off = 1; off < SCAN_B; off <<= 1) {
        int t = (tid >= off) ? lds[tid - off] : 0;
        __syncthreads();
        lds[tid] += t;
        __syncthreads();
    }
    if (i < n) excl[i] = lds[tid] - v;
    if (tid == SCAN_B - 1) blocksums[blockIdx.x] = lds[SCAN_B - 1];
}

__global__ void scan_phaseB(int* blocksums, int nb) {
    __shared__ int lds[SCAN_B];
    int tid = threadIdx.x;
    int v = (tid < nb) ? blocksums[tid] : 0;
    lds[tid] = v;
    __syncthreads();
    for (int off = 1; off < SCAN_B; off <<= 1) {
        int t = (tid >= off) ? lds[tid - off] : 0;
        __syncthreads();
        lds[tid] += t;
        __syncthreads();
    }
    if (tid < nb) blocksums[tid] = lds[tid] - v;
}

__global__ void scan_phaseC(int* __restrict__ offs, const int* __restrict__ blocksums,
                            int* __restrict__ cursor, int n, int E) {
    int i = blockIdx.x * blockDim.x + threadIdx.x;
    if (i < n) {
        int o = offs[i] + blocksums[i / SCAN_B];
        offs[i] = o;
        if (cursor) cursor[i] = o;
    } else if (i == n) {
        offs[n] = E;
    }
}

// ---------------- fill: atomic-free via (shard, rank), int4 ----------------
__global__ void fill_rank_kernel(const int* __restrict__ src, const int* __restrict__ dst,
                                 const int* __restrict__ rank, const int* __restrict__ offs,
                                 int* __restrict__ ssort, int E, int S) {
    int e0 = ((int)blockIdx.x * 256 + (int)threadIdx.x) * 4;
    if (e0 >= E) return;
    int s = (e0 >> 10) & (S - 1);   // same window for e0..e0+3
    if (e0 + 3 < E) {
        int4 d = ((const int4*)dst)[e0 >> 2];
        int4 sr = ((const int4*)src)[e0 >> 2];
        int4 r = ((const int4*)rank)[e0 >> 2];
        ssort[offs[(size_t)d.x * S + s] + r.x] = sr.x;
        ssort[offs[(size_t)d.y * S + s] + r.y] = sr.y;
        ssort[offs[(size_t)d.z * S + s] + r.z] = sr.z;
        ssort[offs[(size_t)d.w * S + s] + r.w] = sr.w;
    } else {
        for (int e = e0; e < E; ++e)
            ssort[offs[(size_t)dst[e] * S + s] + rank[e]] = src[e];
    }
}

// fallback when rank[] doesn't fit (S==1): cursor atomics
__global__ void fill_cursor_kernel(const int* __restrict__ src, const int* __restrict__ dst,
                                   int* __restrict__ cursor, int* __restrict__ ssort, int E) {
    int e = (int)blockIdx.x * 256 + (int)threadIdx.x;
    if (e < E) {
        int pos = atomicAdd(&cursor[dst[e]], 1);
        ssort[pos] = src[e];
    }
}

// ------- layer1 tail: b1 + relu + compact dense2 (h@W2 -> p) -------
__device__ __forceinline__ void layer1_tail(float acc, int lane, int node,
                                            const float* __restrict__ b1,
                                            const float* __restrict__ W2,
                                            float* __restrict__ p)
{
    float h = fmaxf(acc + b1[lane], 0.f);
    int j = lane & 15, ks = lane >> 4;
    float pp = 0.f;
#pragma unroll
    for (int i = 0; i < 16; ++i) {
        int kk = ks * 16 + i;
        float hk = __shfl(h, kk, 64);          // broadcast h[kk] from lane kk
        pp = fmaf(hk, W2[kk * 16 + j], pp);
    }
    pp += __shfl_xor(pp, 16, 64);
    pp += __shfl_xor(pp, 32, 64);
    if (ks == 0) p[(size_t)node * 16 + j] = pp;
}

// ---------- layer1: gather fW1 rows, float2/lane, up to 16 edges in flight ----------
__global__ __launch_bounds__(256) void layer1_f32_kernel(
    const float2* __restrict__ fW1_2, const int* __restrict__ offs,
    const int* __restrict__ ssort, const float* __restrict__ b1,
    const float* __restrict__ W2, float* __restrict__ p, int n_nodes, int S)
{
    int lane = threadIdx.x & 63;
    int w = threadIdx.x >> 6;
    int node = blockIdx.x * 4 + w;
    if (node >= n_nodes) return;            // no barriers below
    int beg = offs[(size_t)node * S], end = offs[(size_t)node * S + S];
    int half = lane >> 5;                   // which edge of the pair
    int sl = lane & 31;                     // col pair -> cols 2sl, 2sl+1
    float ax = 0.f, ay = 0.f;
    int k = beg + half;
    for (; k + 14 < end; k += 16) {         // 16 edges in flight per wave
        int s0 = ssort[k],      s1 = ssort[k + 2],  s2 = ssort[k + 4],  s3 = ssort[k + 6];
        int s4 = ssort[k + 8],  s5 = ssort[k + 10], s6 = ssort[k + 12], s7 = ssort[k + 14];
        float2 v0 = fW1_2[(size_t)s0 * 32 + sl];
        float2 v1 = fW1_2[(size_t)s1 * 32 + sl];
        float2 v2 = fW1_2[(size_t)s2 * 32 + sl];
        float2 v3 = fW1_2[(size_t)s3 * 32 + sl];
        float2 v4 = fW1_2[(size_t)s4 * 32 + sl];
        float2 v5 = fW1_2[(size_t)s5 * 32 + sl];
        float2 v6 = fW1_2[(size_t)s6 * 32 + sl];
        float2 v7 = fW1_2[(size_t)s7 * 32 + sl];
        ax += ((v0.x + v1.x) + (v2.x + v3.x)) + ((v4.x + v5.x) + (v6.x + v7.x));
        ay += ((v0.y + v1.y) + (v2.y + v3.y)) + ((v4.y + v5.y) + (v6.y + v7.y));
    }
    for (; k + 6 < end; k += 8) {
        int s0 = ssort[k], s1 = ssort[k + 2], s2 = ssort[k + 4], s3 = ssort[k + 6];
        float2 v0 = fW1_2[(size_t)s0 * 32 + sl];
        float2 v1 = fW1_2[(size_t)s1 * 32 + sl];
        float2 v2 = fW1_2[(size_t)s2 * 32 + sl];
        float2 v3 = fW1_2[(size_t)s3 * 32 + sl];
        ax += (v0.x + v1.x) + (v2.x + v3.x);
        ay += (v0.y + v1.y) + (v2.y + v3.y);
    }
    for (; k < end; k += 2) {
        float2 v = fW1_2[(size_t)ssort[k] * 32 + sl];
        ax += v.x;
        ay += v.y;
    }
    ax += __shfl_xor(ax, 32, 64);
    ay += __shfl_xor(ay, 32, 64);
    // redistribute (col-pair layout on 32 lanes) -> one col per lane
    float am = __shfl(ax, lane >> 1, 64);
    float bm = __shfl(ay, lane >> 1, 64);
    float acc = (lane & 1) ? bm : am;
    layer1_tail(acc, lane, node, b1, W2, p);
}

// ---------- layer2: wave/node, float2 per lane, 16 edges in flight ----------
__global__ __launch_bounds__(256) void layer2_kernel(
    const float2* __restrict__ p2, const int* __restrict__ offs,
    const int* __restrict__ ssort, const float* __restrict__ b2,
    float* __restrict__ out, int n_nodes, int S)
{
    int lane = threadIdx.x & 63;
    int w = threadIdx.x >> 6;
    int node = blockIdx.x * 4 + w;
    if (node >= n_nodes) return;
    int slot = lane >> 3;   // edge slot 0..7
    int cp = lane & 7;      // column pair -> cols 2cp, 2cp+1
    int beg = offs[(size_t)node * S], end = offs[(size_t)node * S + S];
    float ax = 0.f, ay = 0.f;
    int k = beg + slot;
    for (; k + 8 < end; k += 16) {      // 16 edges in flight
        int s0 = ssort[k], s1 = ssort[k + 8];
        float2 v0 = p2[(size_t)s0 * 8 + cp];
        float2 v1 = p2[(size_t)s1 * 8 + cp];
        ax += v0.x + v1.x;
        ay += v0.y + v1.y;
    }
    for (; k < end; k += 8) {
        float2 v = p2[(size_t)ssort[k] * 8 + cp];
        ax += v.x;
        ay += v.y;
    }
    ax += __shfl_xor(ax, 8, 64);  ay += __shfl_xor(ay, 8, 64);
    ax += __shfl_xor(ax, 16, 64); ay += __shfl_xor(ay, 16, 64);
    ax += __shfl_xor(ax, 32, 64); ay += __shfl_xor(ay, 32, 64);
    float2 bb = ((const float2*)b2)[cp];
    float vx = ax + bb.x, vy = ay + bb.y;
    float m = fmaxf(vx, vy);
    m = fmaxf(m, __shfl_xor(m, 1, 64));
    m = fmaxf(m, __shfl_xor(m, 2, 64));
    m = fmaxf(m, __shfl_xor(m, 4, 64));
    float ex = __expf(vx - m), ey = __expf(vy - m);
    float s = ex + ey;
    s += __shfl_xor(s, 1, 64);
    s += __shfl_xor(s, 2, 64);
    s += __shfl_xor(s, 4, 64);
    if (slot == 0) {
        float inv = 1.f / s;
        float2 o; o.x = ex * inv; o.y = ey * inv;
        ((float2*)out)[(size_t)node * 8 + cp] = o;
    }
}

extern "C" void kernel_launch(void* const* d_in, const int* in_sizes, int n_in,
                              void* d_out, int out_size, void* d_ws, size_t ws_size,
                              hipStream_t stream) {
    const float* feat = (const float*)d_in[0];
    const float* W1   = (const float*)d_in[1];
    const float* b1   = (const float*)d_in[2];
    const float* W2   = (const float*)d_in[3];
    const float* b2   = (const float*)d_in[4];
    const int*   src  = (const int*)d_in[5];
    const int*   dst  = (const int*)d_in[6];

    int N = in_sizes[0] / 64;
    int E = in_sizes[5];

    // ws ladder: (S=8, rank) -> (S=1, rank) -> (S=1, cursor)
    // layout: p[16N] | fW1[64N] | counts[N*S] | offs[N*S+1] | cursor[N*S] | bsums | ssort[E] | rank[E]
    auto need = [&](int S, bool rnk) -> size_t {
        size_t ints = (size_t)N * S * 3 + 1 + SCAN_B + (size_t)E + (rnk ? (size_t)E : 0);
        return ((size_t)N * 80) * 4 + ints * 4;
    };
    int S, log2S; bool use_rank;
    if (ws_size >= need(8, true))      { S = 8; log2S = 3; use_rank = true; }
    else if (ws_size >= need(1, true)) { S = 1; log2S = 0; use_rank = true; }
    else                               { S = 1; log2S = 0; use_rank = false; }

    float* p      = (float*)d_ws;
    float* fW1    = p + (size_t)N * 16;
    int*   counts = (int*)(fW1 + (size_t)N * 64);
    int*   offs   = counts + (size_t)N * S;
    int*   cursor = offs + (size_t)N * S + 1;
    int*   bsums  = cursor + (size_t)N * S;
    int*   ssort  = bsums + SCAN_B;
    int*   rank   = ssort + E;
    float* out    = (float*)d_out;

    int nS = N * S;
    int nb = (nS + SCAN_B - 1) / SCAN_B;
    int histBlocks = (E + 255) / 256;

    hipMemsetAsync(counts, 0, (size_t)nS * sizeof(int), stream);

    prep_kernel<<<FW1B + histBlocks, 256, 0, stream>>>(
        feat, W1, fW1, dst, counts, use_rank ? rank : cursor /*scratch*/, N, E, S);

    scan_phaseA<<<nb, SCAN_B, 0, stream>>>(counts, offs, bsums, nS, N, log2S);
    scan_phaseB<<<1, SCAN_B, 0, stream>>>(bsums, nb);
    scan_phaseC<<<(nS + 1 + 255) / 256, 256, 0, stream>>>(
        offs, bsums, use_rank ? nullptr : cursor, nS, E);

    if (use_rank) {
        fill_rank_kernel<<<(E + 1023) / 1024, 256, 0, stream>>>(src, dst, rank, offs, ssort, E, S);
    } else {
        fill_cursor_kernel<<<(E + 255) / 256, 256, 0, stream>>>(src, dst, cursor, ssort, E);
    }

    layer1_f32_kernel<<<(N + 3) / 4, 256, 0, stream>>>((const float2*)fW1, offs, ssort, b1, W2, p, N, S);
    layer2_kernel<<<(N + 3) / 4, 256, 0, stream>>>((const float2*)p, offs, ssort, b2, out, N, S);
}

// Round 9
// 236.803 us; speedup vs baseline: 1.1714x; 1.1157x over previous
//
#include <hip/hip_runtime.h>
#include <math.h>

// GCN 2-layer, pull-based (CSR by dst via counting sort), no float atomics.
// Algebra: segsum commutes with right-matmul -> both matmuls hoisted:
//   fW1 = feat@W1 (one pass over N rows)
//   h   = relu(segsum(fW1[src]) + b1)
//   p   = h@W2 (compact per-node) ; out = softmax(segsum(p[src]) + b2)
// R8: prep was fw1-LDS-bound (128 DS instrs/node from shfl+ds_read; WRITE_SIZE
//     invariant across all sharding variants proved atomics weren't the wall).
//     fw1 rebuilt: W1 column per lane in 64 VGPRs, feat tile in LDS, 16
//     broadcast ds_read_b128 + 64 FMA per node (8x less DS). Sharding
//     reverted to S=1 (it was a no-op).

#define SCAN_B 1024
#define FW1B   1024   // blocks of the fused grid doing fw1

// ---------------- fused prep: blocks [0,FW1B) do fW1=feat@W1, rest hist ----------------
__global__ __launch_bounds__(256) void prep_kernel(
    const float4* __restrict__ feat4, const float* __restrict__ W1,
    float* __restrict__ fW1, const int* __restrict__ dst,
    int* __restrict__ counts, int* __restrict__ rank, int n_nodes, int E)
{
    __shared__ float ft[32][64];          // 8 KB feat tile
    if ((int)blockIdx.x >= FW1B) {
        // ---- histogram: 1 edge/thread, rank = atomicAdd return ----
        int e = ((int)blockIdx.x - FW1B) * 256 + threadIdx.x;
        if (e < E) rank[e] = atomicAdd(&counts[dst[e]], 1);
        return;
    }
    // ---- fW1: lane j holds W1[:,j] in 64 VGPRs (coalesced loads, once) ----
    int lane = threadIdx.x & 63, w = threadIdx.x >> 6;
    float wcol[64];
#pragma unroll
    for (int k = 0; k < 64; ++k) wcol[k] = W1[k * 64 + lane];

    int ntiles = (n_nodes + 31) >> 5;
    for (int tile = blockIdx.x; tile < ntiles; tile += FW1B) {
        int base = tile * 32;
        __syncthreads();                  // protect previous iter's reads
        // stage 32 rows via float4 (coalesced)
#pragma unroll
        for (int it = 0; it < 2; ++it) {
            int i = it * 256 + threadIdx.x;
            int r = i >> 4, c = i & 15;
            int gn = base + r;
            ((float4*)ft[r])[c] = (gn < n_nodes) ? feat4[(size_t)gn * 16 + c]
                                                 : make_float4(0.f, 0.f, 0.f, 0.f);
        }
        __syncthreads();
        // wave w computes nodes base+8w .. base+8w+7; per node: 16 broadcast
        // ds_read_b128 + 64 fma (wcol indexed by constants -> stays in VGPRs)
        for (int i = 0; i < 8; ++i) {
            int r = w * 8 + i;
            int gn = base + r;
            if (gn >= n_nodes) break;
            float acc = 0.f;
            const float4* row4 = (const float4*)ft[r];
#pragma unroll
            for (int k4 = 0; k4 < 16; ++k4) {
                float4 f = row4[k4];      // uniform address -> LDS broadcast
                acc = fmaf(f.x, wcol[k4 * 4 + 0],
                      fmaf(f.y, wcol[k4 * 4 + 1],
                      fmaf(f.z, wcol[k4 * 4 + 2],
                      fmaf(f.w, wcol[k4 * 4 + 3], acc))));
            }
            fW1[(size_t)gn * 64 + lane] = acc;
        }
    }
}

// ---------------- scan over N counters ----------------
__global__ void scan_phaseA(const int* __restrict__ counts, int* __restrict__ excl,
                            int* __restrict__ blocksums, int n) {
    __shared__ int lds[SCAN_B];
    int tid = threadIdx.x;
    int i = blockIdx.x * SCAN_B + tid;
    int v = (i < n) ? counts[i] : 0;
    lds[tid] = v;
    __syncthreads();
    for (int off = 1; off < SCAN_B; off <<= 1) {
        int t = (tid >= off) ? lds[tid - off] : 0;
        __syncthreads();
        lds[tid] += t;
        __syncthreads();
    }
    if (i < n) excl[i] = lds[tid] - v;
    if (tid == SCAN_B - 1) blocksums[blockIdx.x] = lds[SCAN_B - 1];
}

__global__ void scan_phaseB(int* blocksums, int nb) {
    __shared__ int lds[SCAN_B];
    int tid = threadIdx.x;
    int v = (tid < nb) ? blocksums[tid] : 0;
    lds[tid] = v;
    __syncthreads();
    for (int off = 1; off < SCAN_B; off <<= 1) {
        int t = (tid >= off) ? lds[tid - off] : 0;
        __syncthreads();
        lds[tid] += t;
        __syncthreads();
    }
    if (tid < nb) blocksums[tid] = lds[tid] - v;
}

__global__ void scan_phaseC(int* __restrict__ offs, const int* __restrict__ blocksums,
                            int* __restrict__ cursor, int n, int E) {
    int i = blockIdx.x * blockDim.x + threadIdx.x;
    if (i < n) {
        int o = offs[i] + blocksums[i / SCAN_B];
        offs[i] = o;
        if (cursor) cursor[i] = o;
    } else if (i == n) {
        offs[n] = E;
    }
}

// ---------------- fill: atomic-free via rank, int4 ----------------
__global__ void fill_rank_kernel(const int* __restrict__ src, const int* __restrict__ dst,
                                 const int* __restrict__ rank, const int* __restrict__ offs,
                                 int* __restrict__ ssort, int E) {
    int e0 = ((int)blockIdx.x * 256 + (int)threadIdx.x) * 4;
    if (e0 >= E) return;
    if (e0 + 3 < E) {
        int4 d = ((const int4*)dst)[e0 >> 2];
        int4 sr = ((const int4*)src)[e0 >> 2];
        int4 r = ((const int4*)rank)[e0 >> 2];
        ssort[offs[d.x] + r.x] = sr.x;
        ssort[offs[d.y] + r.y] = sr.y;
        ssort[offs[d.z] + r.z] = sr.z;
        ssort[offs[d.w] + r.w] = sr.w;
    } else {
        for (int e = e0; e < E; ++e)
            ssort[offs[dst[e]] + rank[e]] = src[e];
    }
}

// fallback when rank[] doesn't fit: cursor atomics
__global__ void fill_cursor_kernel(const int* __restrict__ src, const int* __restrict__ dst,
                                   int* __restrict__ cursor, int* __restrict__ ssort, int E) {
    int e = (int)blockIdx.x * 256 + (int)threadIdx.x;
    if (e < E) {
        int pos = atomicAdd(&cursor[dst[e]], 1);
        ssort[pos] = src[e];
    }
}

// ------- layer1 tail: b1 + relu + compact dense2 (h@W2 -> p) -------
__device__ __forceinline__ void layer1_tail(float acc, int lane, int node,
                                            const float* __restrict__ b1,
                                            const float* __restrict__ W2,
                                            float* __restrict__ p)
{
    float h = fmaxf(acc + b1[lane], 0.f);
    int j = lane & 15, ks = lane >> 4;
    float pp = 0.f;
#pragma unroll
    for (int i = 0; i < 16; ++i) {
        int kk = ks * 16 + i;
        float hk = __shfl(h, kk, 64);          // broadcast h[kk] from lane kk
        pp = fmaf(hk, W2[kk * 16 + j], pp);
    }
    pp += __shfl_xor(pp, 16, 64);
    pp += __shfl_xor(pp, 32, 64);
    if (ks == 0) p[(size_t)node * 16 + j] = pp;
}

// ---------- layer1: gather fW1 rows, float2/lane, up to 16 edges in flight ----------
__global__ __launch_bounds__(256) void layer1_f32_kernel(
    const float2* __restrict__ fW1_2, const int* __restrict__ offs,
    const int* __restrict__ ssort, const float* __restrict__ b1,
    const float* __restrict__ W2, float* __restrict__ p, int n_nodes)
{
    int lane = threadIdx.x & 63;
    int w = threadIdx.x >> 6;
    int node = blockIdx.x * 4 + w;
    if (node >= n_nodes) return;            // no barriers below
    int beg = offs[node], end = offs[node + 1];
    int half = lane >> 5;                   // which edge of the pair
    int sl = lane & 31;                     // col pair -> cols 2sl, 2sl+1
    float ax = 0.f, ay = 0.f;
    int k = beg + half;
    for (; k + 14 < end; k += 16) {         // 16 edges in flight per wave
        int s0 = ssort[k],      s1 = ssort[k + 2],  s2 = ssort[k + 4],  s3 = ssort[k + 6];
        int s4 = ssort[k + 8],  s5 = ssort[k + 10], s6 = ssort[k + 12], s7 = ssort[k + 14];
        float2 v0 = fW1_2[(size_t)s0 * 32 + sl];
        float2 v1 = fW1_2[(size_t)s1 * 32 + sl];
        float2 v2 = fW1_2[(size_t)s2 * 32 + sl];
        float2 v3 = fW1_2[(size_t)s3 * 32 + sl];
        float2 v4 = fW1_2[(size_t)s4 * 32 + sl];
        float2 v5 = fW1_2[(size_t)s5 * 32 + sl];
        float2 v6 = fW1_2[(size_t)s6 * 32 + sl];
        float2 v7 = fW1_2[(size_t)s7 * 32 + sl];
        ax += ((v0.x + v1.x) + (v2.x + v3.x)) + ((v4.x + v5.x) + (v6.x + v7.x));
        ay += ((v0.y + v1.y) + (v2.y + v3.y)) + ((v4.y + v5.y) + (v6.y + v7.y));
    }
    for (; k + 6 < end; k += 8) {
        int s0 = ssort[k], s1 = ssort[k + 2], s2 = ssort[k + 4], s3 = ssort[k + 6];
        float2 v0 = fW1_2[(size_t)s0 * 32 + sl];
        float2 v1 = fW1_2[(size_t)s1 * 32 + sl];
        float2 v2 = fW1_2[(size_t)s2 * 32 + sl];
        float2 v3 = fW1_2[(size_t)s3 * 32 + sl];
        ax += (v0.x + v1.x) + (v2.x + v3.x);
        ay += (v0.y + v1.y) + (v2.y + v3.y);
    }
    for (; k < end; k += 2) {
        float2 v = fW1_2[(size_t)ssort[k] * 32 + sl];
        ax += v.x;
        ay += v.y;
    }
    ax += __shfl_xor(ax, 32, 64);
    ay += __shfl_xor(ay, 32, 64);
    // redistribute (col-pair layout on 32 lanes) -> one col per lane
    float am = __shfl(ax, lane >> 1, 64);
    float bm = __shfl(ay, lane >> 1, 64);
    float acc = (lane & 1) ? bm : am;
    layer1_tail(acc, lane, node, b1, W2, p);
}

// ---------- layer2: wave/node, float2 per lane, 16 edges in flight ----------
__global__ __launch_bounds__(256) void layer2_kernel(
    const float2* __restrict__ p2, const int* __restrict__ offs,
    const int* __restrict__ ssort, const float* __restrict__ b2,
    float* __restrict__ out, int n_nodes)
{
    int lane = threadIdx.x & 63;
    int w = threadIdx.x >> 6;
    int node = blockIdx.x * 4 + w;
    if (node >= n_nodes) return;
    int slot = lane >> 3;   // edge slot 0..7
    int cp = lane & 7;      // column pair -> cols 2cp, 2cp+1
    int beg = offs[node], end = offs[node + 1];
    float ax = 0.f, ay = 0.f;
    int k = beg + slot;
    for (; k + 8 < end; k += 16) {      // 16 edges in flight
        int s0 = ssort[k], s1 = ssort[k + 8];
        float2 v0 = p2[(size_t)s0 * 8 + cp];
        float2 v1 = p2[(size_t)s1 * 8 + cp];
        ax += v0.x + v1.x;
        ay += v0.y + v1.y;
    }
    for (; k < end; k += 8) {
        float2 v = p2[(size_t)ssort[k] * 8 + cp];
        ax += v.x;
        ay += v.y;
    }
    ax += __shfl_xor(ax, 8, 64);  ay += __shfl_xor(ay, 8, 64);
    ax += __shfl_xor(ax, 16, 64); ay += __shfl_xor(ay, 16, 64);
    ax += __shfl_xor(ax, 32, 64); ay += __shfl_xor(ay, 32, 64);
    float2 bb = ((const float2*)b2)[cp];
    float vx = ax + bb.x, vy = ay + bb.y;
    float m = fmaxf(vx, vy);
    m = fmaxf(m, __shfl_xor(m, 1, 64));
    m = fmaxf(m, __shfl_xor(m, 2, 64));
    m = fmaxf(m, __shfl_xor(m, 4, 64));
    float ex = __expf(vx - m), ey = __expf(vy - m);
    float s = ex + ey;
    s += __shfl_xor(s, 1, 64);
    s += __shfl_xor(s, 2, 64);
    s += __shfl_xor(s, 4, 64);
    if (slot == 0) {
        float inv = 1.f / s;
        float2 o; o.x = ex * inv; o.y = ey * inv;
        ((float2*)out)[(size_t)node * 8 + cp] = o;
    }
}

extern "C" void kernel_launch(void* const* d_in, const int* in_sizes, int n_in,
                              void* d_out, int out_size, void* d_ws, size_t ws_size,
                              hipStream_t stream) {
    const float* feat = (const float*)d_in[0];
    const float* W1   = (const float*)d_in[1];
    const float* b1   = (const float*)d_in[2];
    const float* W2   = (const float*)d_in[3];
    const float* b2   = (const float*)d_in[4];
    const int*   src  = (const int*)d_in[5];
    const int*   dst  = (const int*)d_in[6];

    int N = in_sizes[0] / 64;
    int E = in_sizes[5];

    // layout: p[16N] | fW1[64N] | counts[N] | offs[N+1] | cursor[N] | bsums | ssort[E] | rank[E]
    float* p      = (float*)d_ws;
    float* fW1    = p + (size_t)N * 16;
    int*   counts = (int*)(fW1 + (size_t)N * 64);
    int*   offs   = counts + N;
    int*   cursor = offs + N + 1;
    int*   bsums  = cursor + N;
    int*   ssort  = bsums + SCAN_B;
    int*   rank   = ssort + E;
    size_t need_rank = (size_t)(rank + E - (int*)d_ws) * sizeof(int);
    bool use_rank = ws_size >= need_rank;
    float* out = (float*)d_out;

    int nb = (N + SCAN_B - 1) / SCAN_B;
    int histBlocks = (E + 255) / 256;

    hipMemsetAsync(counts, 0, (size_t)N * sizeof(int), stream);

    prep_kernel<<<FW1B + histBlocks, 256, 0, stream>>>(
        (const float4*)feat, W1, fW1, dst, counts,
        use_rank ? rank : cursor /*scratch*/, N, E);

    scan_phaseA<<<nb, SCAN_B, 0, stream>>>(counts, offs, bsums, N);
    scan_phaseB<<<1, SCAN_B, 0, stream>>>(bsums, nb);
    scan_phaseC<<<(N + 1 + 255) / 256, 256, 0, stream>>>(
        offs, bsums, use_rank ? nullptr : cursor, N, E);

    if (use_rank) {
        fill_rank_kernel<<<(E + 1023) / 1024, 256, 0, stream>>>(src, dst, rank, offs, ssort, E);
    } else {
        fill_cursor_kernel<<<(E + 255) / 256, 256, 0, stream>>>(src, dst, cursor, ssort, E);
    }

    layer1_f32_kernel<<<(N + 3) / 4, 256, 0, stream>>>((const float2*)fW1, offs, ssort, b1, W2, p, N);
    layer2_kernel<<<(N + 3) / 4, 256, 0, stream>>>((const float2*)p, offs, ssort, b2, out, N);
}